// Round 16
// baseline (1273.258 us; speedup 1.0000x reference)
//
#include <hip/hip_runtime.h>
#include <math.h>

#define IN_F 1433
#define HID  16
#define OUTC 7
#define SCAN_T 1024

// K1 geometry (v8: 3-phase KCH=560, 38KB LDS, forced 4 blocks/CU)
#define K1_THREADS 512
#define K1_ROWS_W  8
#define K1_ROWS_B  64
#define KCH        560
#define LDSW       17
#define K1_LDS_FLOATS (KCH * LDSW)   // 9520 floats = 38080 B -> 4 blocks/CU

// bucket geometry
#define RPB      128               // rows per bucket (r_local: 7 bits)
#define BCAP     4480              // bucket capacity
#define PCH      2048              // partition chunk (512 thr x 4 edges)
#define OVF_CAP  131072            // spill capacity

__host__ __device__ __forceinline__ int imin(int a, int b) { return a < b ? a : b; }

// ---------------------------------------------------------------------------
__global__ __launch_bounds__(256) void zero_i32(int4* __restrict__ p, int n4)
{
    int i = blockIdx.x * blockDim.x + threadIdx.x;
    if (i < n4) p[i] = make_int4(0, 0, 0, 0);
}

// ---------------------------------------------------------------------------
// K1 v8 body: XW = x @ W1, 3 phases of KCH k's staged in LDS.
// Predication-free main chunks (only final partial chunk predicated).
// lane = j4*16 + ks; acc[8][4]/lane; butterfly over ks; float4 stores.
// ---------------------------------------------------------------------------
__device__ __forceinline__ void k1_body(
    const float* __restrict__ x, const float* __restrict__ W1,
    float* __restrict__ XW, int N, int vbid, float* sW)
{
    const int wave = threadIdx.x >> 6;
    const int lane = threadIdx.x & 63;
    const int ks   = lane & 15;
    const int j4   = lane >> 4;
    const int row0 = vbid * K1_ROWS_B + wave * K1_ROWS_W;

    int xoff[K1_ROWS_W];
#pragma unroll
    for (int r = 0; r < K1_ROWS_W; ++r) {
        int row = row0 + r;
        if (row > N - 1) row = N - 1;
        if (row < 0) row = 0;
        xoff[r] = row * IN_F;
    }

    float acc[K1_ROWS_W][4];
#pragma unroll
    for (int r = 0; r < K1_ROWS_W; ++r)
#pragma unroll
        for (int jj = 0; jj < 4; ++jj) acc[r][jj] = 0.f;

#pragma unroll 1
    for (int p = 0; p < 3; ++p) {
        const int pbase = p * KCH;                 // 0, 560, 1120
        const int pk    = imin(KCH, IN_F - pbase); // 560, 560, 313
        if (p) __syncthreads();                    // prev phase fully read
        for (int f = threadIdx.x; f < pk * HID; f += K1_THREADS)
            sW[(f >> 4) * LDSW + (f & 15)] = W1[pbase * HID + f];
        __syncthreads();

        const int nfull = pk >> 4;                 // 35, 35, 19
#pragma unroll 2
        for (int c = 0; c < nfull; ++c) {
            const int kloc = c * 16 + ks;
            const float* wr = sW + (size_t)kloc * LDSW + j4 * 4;
            float w0 = wr[0], w1 = wr[1], w2 = wr[2], w3 = wr[3];
            float xv[K1_ROWS_W];
#pragma unroll
            for (int r = 0; r < K1_ROWS_W; ++r)
                xv[r] = x[(size_t)xoff[r] + pbase + kloc];
#pragma unroll
            for (int r = 0; r < K1_ROWS_W; ++r) {
                acc[r][0] += xv[r] * w0;
                acc[r][1] += xv[r] * w1;
                acc[r][2] += xv[r] * w2;
                acc[r][3] += xv[r] * w3;
            }
        }

        if (pk & 15) {                             // only phase 2 (313)
            const int kloc = nfull * 16 + ks;      // 304..319, < KCH
            const bool ok = (kloc < pk);
            const float* wr = sW + (size_t)kloc * LDSW + j4 * 4;
            float w0 = wr[0], w1 = wr[1], w2 = wr[2], w3 = wr[3];
            float xv[K1_ROWS_W];
#pragma unroll
            for (int r = 0; r < K1_ROWS_W; ++r)
                xv[r] = ok ? x[(size_t)xoff[r] + pbase + kloc] : 0.f;
#pragma unroll
            for (int r = 0; r < K1_ROWS_W; ++r) {
                acc[r][0] += xv[r] * w0;
                acc[r][1] += xv[r] * w1;
                acc[r][2] += xv[r] * w2;
                acc[r][3] += xv[r] * w3;
            }
        }
    }

    // butterfly over the 16 ks-lanes (lane bits 0..3)
#pragma unroll
    for (int m = 1; m <= 8; m <<= 1)
#pragma unroll
        for (int r = 0; r < K1_ROWS_W; ++r)
#pragma unroll
            for (int jj = 0; jj < 4; ++jj)
                acc[r][jj] += __shfl_xor(acc[r][jj], m);

    if (ks == 0) {
#pragma unroll
        for (int r = 0; r < K1_ROWS_W; ++r) {
            const int row = row0 + r;
            if (row >= 0 && row < N) {
                float4 o = make_float4(acc[r][0], acc[r][1], acc[r][2], acc[r][3]);
                *(float4*)(XW + (size_t)row * HID + j4 * 4) = o;
            }
        }
    }
}

// ---------------------------------------------------------------------------
// partition_body (proven round 14-15)
// ---------------------------------------------------------------------------
__device__ __forceinline__ void partition_body(
    const int* __restrict__ arow, const int* __restrict__ acol,
    const float* __restrict__ aval, int* __restrict__ cursor,
    int2* __restrict__ buckets, int* __restrict__ ovf, int* __restrict__ ovfc,
    int E, int nbuk, int sb, int nsb, int* hist)
{
    const int nch = (E + PCH - 1) / PCH;
    for (int ch = sb; ch < nch; ch += nsb) {
        const int e0 = ch * PCH;
        const int e1 = imin(e0 + PCH, E);
        for (int b = threadIdx.x; b < nbuk; b += K1_THREADS) hist[b] = 0;
        __syncthreads();

        int rr[4], cc[4]; float vv[4];
        int nl = 0;
        const int base = e0 + threadIdx.x * 4;
        if (base + 3 < e1) {
            int4 r4 = *(const int4*)(arow + base);
            int4 c4 = *(const int4*)(acol + base);
            float4 v4 = *(const float4*)(aval + base);
            rr[0]=r4.x; rr[1]=r4.y; rr[2]=r4.z; rr[3]=r4.w;
            cc[0]=c4.x; cc[1]=c4.y; cc[2]=c4.z; cc[3]=c4.w;
            vv[0]=v4.x; vv[1]=v4.y; vv[2]=v4.z; vv[3]=v4.w;
            nl = 4;
        } else {
            for (int i = base; i < e1 && nl < 4; ++i) {
                rr[nl] = arow[i]; cc[nl] = acol[i]; vv[nl] = aval[i];
                ++nl;
            }
        }
        for (int u = 0; u < nl; ++u) atomicAdd(&hist[rr[u] >> 7], 1);
        __syncthreads();

        for (int b = threadIdx.x; b < nbuk; b += K1_THREADS) {
            const int h = hist[b];
            hist[b] = (h > 0) ? atomicAdd(&cursor[b], h) : 0;
        }
        __syncthreads();

        for (int u = 0; u < nl; ++u) {
            const int b = rr[u] >> 7;
            const int pos = atomicAdd(&hist[b], 1);
            if (pos < BCAP) {
                buckets[(size_t)b * BCAP + pos] =
                    make_int2(((rr[u] & (RPB - 1)) << 17) | cc[u],
                              __float_as_int(vv[u]));
            } else {
                int op = atomicAdd(ovfc, 1);
                if (op < OVF_CAP) {
                    ovf[3 * op]     = rr[u];
                    ovf[3 * op + 1] = cc[u];
                    ovf[3 * op + 2] = __float_as_int(vv[u]);
                }
            }
        }
        __syncthreads();
    }
}

// ---------------------------------------------------------------------------
// Fat kernel: K1 || partition. Every 4th block is aux.
// __launch_bounds__(512, 8): force VGPR<=64 -> 4 blocks/CU with 38KB LDS.
// ---------------------------------------------------------------------------
__global__ __launch_bounds__(K1_THREADS, 8) void k1_partition(
    const float* __restrict__ x, const float* __restrict__ W1,
    float* __restrict__ XW, int N, int k1b,
    const int* __restrict__ arow, const int* __restrict__ acol,
    const float* __restrict__ aval, int* __restrict__ cursor,
    int2* __restrict__ buckets, int* __restrict__ ovf, int* __restrict__ ovfc,
    int E, int nbuk, int scb)
{
    __shared__ float sW[K1_LDS_FLOATS];
    const int bid = blockIdx.x;
    if ((bid % 4 == 3) && (bid / 4 < scb)) {
        partition_body(arow, acol, aval, cursor, buckets, ovf, ovfc,
                       E, nbuk, bid / 4, scb, (int*)sW);
        return;
    }
    const int k1_idx = bid - imin((bid + 1) / 4, scb);
    if (k1_idx >= k1b) return;
    k1_body(x, W1, XW, N, k1_idx, sW);
}

// ---------------------------------------------------------------------------
// bucket_repack (proven round 15)
// ---------------------------------------------------------------------------
__global__ __launch_bounds__(512) void bucket_repack(
    const int* __restrict__ cursor, int2* __restrict__ buckets,
    int* __restrict__ rowptrB, int* __restrict__ ovf, int* __restrict__ ovfc,
    int nbuk)
{
    __shared__ int2 ebuf[BCAP];
    __shared__ int rcnt[RPB];
    __shared__ int rcur[RPB];
    __shared__ int rbase[RPB + 1];
    const int b = blockIdx.x;
    const int cnt_b = imin(cursor[b], BCAP);
    int2* src = buckets + (size_t)b * BCAP;

    for (int r = threadIdx.x; r < RPB; r += 512) { rcnt[r] = 0; rcur[r] = 0; }
    __syncthreads();

    for (int i = threadIdx.x; i < cnt_b; i += 512)
        atomicAdd(&rcnt[src[i].x >> 17], 1);
    __syncthreads();

    if (threadIdx.x == 0) {
        int run = 0;
        for (int r = 0; r < RPB; ++r) {
            rbase[r] = run;
            run += (rcnt[r] + 1) & ~1;
        }
        rbase[RPB] = run;
    }
    __syncthreads();

    for (int r = threadIdx.x; r < RPB; r += 512) {
        if (rcnt[r] & 1) {
            const int pp = rbase[r] + rcnt[r];
            if (pp < BCAP) ebuf[pp] = make_int2(0, 0);
        }
    }
    __syncthreads();

    for (int i = threadIdx.x; i < cnt_b; i += 512) {
        const int2 ed = src[i];
        const int rl = ed.x >> 17;
        const int pos = rbase[rl] + atomicAdd(&rcur[rl], 1);
        if (pos < BCAP) {
            ebuf[pos] = make_int2(ed.x & 0x1FFFF, ed.y);
        } else {
            int op = atomicAdd(ovfc, 1);
            if (op < OVF_CAP) {
                ovf[3 * op]     = b * RPB + rl;
                ovf[3 * op + 1] = ed.x & 0x1FFFF;
                ovf[3 * op + 2] = ed.y;
            }
        }
    }
    __syncthreads();

    const int total = imin(rbase[RPB], BCAP);
    for (int i = threadIdx.x; i < total; i += 512) src[i] = ebuf[i];
    for (int r = threadIdx.x; r < RPB; r += 512)
        rowptrB[b * (RPB + 1) + r] = imin(rbase[r], BCAP);
    if (threadIdx.x == 0)
        rowptrB[b * (RPB + 1) + RPB] = total;
}

// ---------------------------------------------------------------------------
// Overflow apply
// ---------------------------------------------------------------------------
__global__ __launch_bounds__(256) void ovf_apply16(
    const int* __restrict__ ovf, const int* __restrict__ ovfc,
    const float* __restrict__ XW, float* __restrict__ Hx)
{
    const int n = imin(ovfc[0], OVF_CAP);
    const int tid = blockIdx.x * blockDim.x + threadIdx.x;
    const int stride = gridDim.x * blockDim.x;
    for (int i = tid; i < n; i += stride) {
        const int r = ovf[3 * i], c = ovf[3 * i + 1];
        const float v = __int_as_float(ovf[3 * i + 2]);
        const float* src = XW + (size_t)c * HID;
        float* dst = Hx + (size_t)r * HID;
#pragma unroll
        for (int j = 0; j < HID; ++j) atomicAdd(dst + j, v * src[j]);
    }
}

__global__ __launch_bounds__(256) void ovf_apply7(
    const int* __restrict__ ovf, const int* __restrict__ ovfc,
    const float* __restrict__ h2, float* __restrict__ Ox)
{
    const int n = imin(ovfc[0], OVF_CAP);
    const int tid = blockIdx.x * blockDim.x + threadIdx.x;
    const int stride = gridDim.x * blockDim.x;
    for (int i = tid; i < n; i += stride) {
        const int r = ovf[3 * i], c = ovf[3 * i + 1];
        const float v = __int_as_float(ovf[3 * i + 2]);
        const float* src = h2 + (size_t)c * 8;
        float* dst = Ox + (size_t)r * 8;
#pragma unroll
        for (int j = 0; j < OUTC; ++j) atomicAdd(dst + j, v * src[j]);
    }
}

// ---------------------------------------------------------------------------
// spmm16B: wave-per-row over repacked buckets (+Hx)  [proven round 15]
// ---------------------------------------------------------------------------
__global__ __launch_bounds__(256) void spmm16B(
    const int* __restrict__ rowptrB, const int2* __restrict__ buckets,
    const float* __restrict__ XW, const float* __restrict__ Hx,
    const float* __restrict__ b1, const float* __restrict__ W2,
    float* __restrict__ h2, int N)
{
    const int gw = (int)((blockIdx.x * (size_t)blockDim.x + threadIdx.x) >> 6);
    if (gw >= N) return;
    const int lane = threadIdx.x & 63;
    const int j = lane & 15;
    const int w = lane >> 4;
    const int b  = gw >> 7;
    const int rl = gw & (RPB - 1);
    const int rs = rowptrB[b * (RPB + 1) + rl];
    const int re = rowptrB[b * (RPB + 1) + rl + 1];
    const int2* base = buckets + (size_t)b * BCAP;

    float acc = 0.f;
    int k = rs + w * 4;
    while (k + 4 <= re) {
        const int4* q = (const int4*)(base + k);
        int4 A = q[0], B = q[1];
        acc += __int_as_float(A.y) * XW[(size_t)A.x * HID + j];
        acc += __int_as_float(A.w) * XW[(size_t)A.z * HID + j];
        acc += __int_as_float(B.y) * XW[(size_t)B.x * HID + j];
        acc += __int_as_float(B.w) * XW[(size_t)B.z * HID + j];
        k += 16;
    }
    for (; k < re; ++k) {
        int2 a = base[k];
        acc += __int_as_float(a.y) * XW[(size_t)a.x * HID + j];
    }
    acc += __shfl_xor(acc, 16);
    acc += __shfl_xor(acc, 32);
    acc += Hx[(size_t)gw * HID + j];

    const float h = fmaxf(acc + b1[j], 0.f);
    float p[OUTC];
#pragma unroll
    for (int c = 0; c < OUTC; ++c) p[c] = h * W2[j * OUTC + c];
#pragma unroll
    for (int m = 1; m <= 8; m <<= 1)
#pragma unroll
        for (int c = 0; c < OUTC; ++c) p[c] += __shfl_xor(p[c], m);

    if (lane < 8) {
        float o = p[0];
        o = (lane == 1) ? p[1] : o;
        o = (lane == 2) ? p[2] : o;
        o = (lane == 3) ? p[3] : o;
        o = (lane == 4) ? p[4] : o;
        o = (lane == 5) ? p[5] : o;
        o = (lane == 6) ? p[6] : o;
        if (lane == 7) o = 0.f;
        h2[(size_t)gw * 8 + lane] = o;
    }
}

// ---------------------------------------------------------------------------
// spmm7B: wave-per-row + fused log_softmax (+Ox)  [proven round 15]
// ---------------------------------------------------------------------------
__global__ __launch_bounds__(256) void spmm7B(
    const int* __restrict__ rowptrB, const int2* __restrict__ buckets,
    const float* __restrict__ h2, const float* __restrict__ Ox,
    const float* __restrict__ b2, float* __restrict__ out, int N)
{
    const int gw = (int)((blockIdx.x * (size_t)blockDim.x + threadIdx.x) >> 6);
    if (gw >= N) return;
    const int lane = threadIdx.x & 63;
    const int j = lane & 7;
    const int w = lane >> 3;
    const int b  = gw >> 7;
    const int rl = gw & (RPB - 1);
    const int rs = rowptrB[b * (RPB + 1) + rl];
    const int re = rowptrB[b * (RPB + 1) + rl + 1];
    const int2* base = buckets + (size_t)b * BCAP;

    float acc = 0.f;
    int k = rs + w * 4;
    while (k + 4 <= re) {
        const int4* q = (const int4*)(base + k);
        int4 A = q[0], B = q[1];
        acc += __int_as_float(A.y) * h2[(size_t)A.x * 8 + j];
        acc += __int_as_float(A.w) * h2[(size_t)A.z * 8 + j];
        acc += __int_as_float(B.y) * h2[(size_t)B.x * 8 + j];
        acc += __int_as_float(B.w) * h2[(size_t)B.z * 8 + j];
        k += 32;
    }
    for (; k < re; ++k) {
        int2 a = base[k];
        acc += __int_as_float(a.y) * h2[(size_t)a.x * 8 + j];
    }
    acc += __shfl_xor(acc, 8);
    acc += __shfl_xor(acc, 16);
    acc += __shfl_xor(acc, 32);
    acc += Ox[(size_t)gw * 8 + j];

    const float bias = b2[(j < OUTC) ? j : 0];
    const float val  = acc + bias;
    float mx = (j < OUTC) ? val : -INFINITY;
    mx = fmaxf(mx, __shfl_xor(mx, 1));
    mx = fmaxf(mx, __shfl_xor(mx, 2));
    mx = fmaxf(mx, __shfl_xor(mx, 4));
    float ex = (j < OUTC) ? expf(val - mx) : 0.f;
    ex += __shfl_xor(ex, 1);
    ex += __shfl_xor(ex, 2);
    ex += __shfl_xor(ex, 4);
    if (lane < OUTC) out[(size_t)gw * OUTC + lane] = val - mx - logf(ex);
}

// ===========================================================================
// Tier-2: CSR path
// ===========================================================================
__device__ __forceinline__ void hist_body(
    const int* __restrict__ arow, int* __restrict__ cnt, int E, int hb, int nhb)
{
    const int tid = hb * K1_THREADS + threadIdx.x;
    const int stride = nhb * K1_THREADS;
    const int E4 = E >> 2;
    const int4* a4 = (const int4*)arow;
    for (int v = tid; v < E4; v += stride) {
        int4 r = a4[v];
        atomicAdd(&cnt[r.x], 1);
        atomicAdd(&cnt[r.y], 1);
        atomicAdd(&cnt[r.z], 1);
        atomicAdd(&cnt[r.w], 1);
    }
    for (int v = E4 * 4 + tid; v < E; v += stride) atomicAdd(&cnt[arow[v]], 1);
}

__device__ __forceinline__ void scatter_body(
    const int* __restrict__ arow, const int* __restrict__ acol,
    const float* __restrict__ aval, int* __restrict__ cursor,
    int2* __restrict__ ecv, int E, int sb, int nsb)
{
    const int tid = sb * K1_THREADS + threadIdx.x;
    const int stride = nsb * K1_THREADS;
    const int E4 = E >> 2;
    const int4*   ar4 = (const int4*)arow;
    const int4*   ac4 = (const int4*)acol;
    const float4* av4 = (const float4*)aval;
    for (int v = tid; v < E4; v += stride) {
        int4 r = ar4[v];
        int4 c = ac4[v];
        float4 val = av4[v];
        int p0 = atomicAdd(&cursor[r.x], 1);
        int p1 = atomicAdd(&cursor[r.y], 1);
        int p2 = atomicAdd(&cursor[r.z], 1);
        int p3 = atomicAdd(&cursor[r.w], 1);
        ecv[p0] = make_int2(c.x, __float_as_int(val.x));
        ecv[p1] = make_int2(c.y, __float_as_int(val.y));
        ecv[p2] = make_int2(c.z, __float_as_int(val.z));
        ecv[p3] = make_int2(c.w, __float_as_int(val.w));
    }
    for (int v = E4 * 4 + tid; v < E; v += stride) {
        int pos = atomicAdd(&cursor[arow[v]], 1);
        ecv[pos] = make_int2(acol[v], __float_as_int(aval[v]));
    }
}

__global__ __launch_bounds__(K1_THREADS, 8) void k1_hist_fused(
    const float* __restrict__ x, const float* __restrict__ W1,
    float* __restrict__ XW, int N, int half1,
    const int* __restrict__ arow, int* __restrict__ cnt, int E, int histB)
{
    __shared__ float sW[K1_LDS_FLOATS];
    const int bid = blockIdx.x;
    if ((bid % 3 == 2) && (bid / 3 < histB)) {
        hist_body(arow, cnt, E, bid / 3, histB);
        return;
    }
    const int k1_idx = bid - imin((bid + 1) / 3, histB);
    if (k1_idx >= half1) return;
    k1_body(x, W1, XW, N, k1_idx, sW);
}

__global__ __launch_bounds__(K1_THREADS, 8) void k1_scatter_fused(
    const float* __restrict__ x, const float* __restrict__ W1,
    float* __restrict__ XW, int N, int half1, int half2,
    const int* __restrict__ arow, const int* __restrict__ acol,
    const float* __restrict__ aval, int* __restrict__ cursor,
    int2* __restrict__ ecv, int E, int scb)
{
    __shared__ float sW[K1_LDS_FLOATS];
    const int bid = blockIdx.x;
    if ((bid % 3 == 2) && (bid / 3 < scb)) {
        scatter_body(arow, acol, aval, cursor, ecv, E, bid / 3, scb);
        return;
    }
    const int k1_idx = bid - imin((bid + 1) / 3, scb) + half1;
    if (k1_idx >= half1 + half2) return;
    k1_body(x, W1, XW, N, k1_idx, sW);
}

__global__ __launch_bounds__(K1_THREADS, 8) void gcn_k1_xw(
    const float* __restrict__ x, const float* __restrict__ W1,
    float* __restrict__ XW, int N)
{
    __shared__ float sW[K1_LDS_FLOATS];
    k1_body(x, W1, XW, N, blockIdx.x, sW);
}

__global__ __launch_bounds__(256) void csr_hist(
    const int* __restrict__ arow, int* __restrict__ cnt, int E)
{
    int e = blockIdx.x * blockDim.x + threadIdx.x;
    if (e < E) atomicAdd(&cnt[arow[e]], 1);
}

__global__ __launch_bounds__(256) void csr_scatter(
    const int* __restrict__ arow, const int* __restrict__ acol,
    const float* __restrict__ aval, int* __restrict__ cursor,
    int2* __restrict__ ecv, int E)
{
    int e = blockIdx.x * blockDim.x + threadIdx.x;
    if (e >= E) return;
    int pos = atomicAdd(&cursor[arow[e]], 1);
    ecv[pos] = make_int2(acol[e], __float_as_int(aval[e]));
}

__global__ __launch_bounds__(SCAN_T) void csr_scan(
    const int* __restrict__ cnt, int* __restrict__ rowptr,
    int* __restrict__ cursor, int N)
{
    __shared__ int sums[SCAN_T];
    const int t = threadIdx.x;
    const int chunk = (((N + SCAN_T - 1) / SCAN_T) + 3) & ~3;
    const int lo = t * chunk;
    int s = 0;
    const bool full = (lo + chunk <= N);
    if (full) {
        const int4* c4 = (const int4*)(cnt + lo);
#pragma unroll 4
        for (int i = 0; i < chunk / 4; ++i) {
            int4 v = c4[i];
            s += ((v.x + 1) & ~1) + ((v.y + 1) & ~1)
               + ((v.z + 1) & ~1) + ((v.w + 1) & ~1);
        }
    } else {
        const int hi = (lo + chunk < N) ? lo + chunk : N;
        for (int i = lo; i < hi; ++i) s += (cnt[i] + 1) & ~1;
    }
    sums[t] = s;
    __syncthreads();
    for (int d = 1; d < SCAN_T; d <<= 1) {
        int a = sums[t];
        int b = (t >= d) ? sums[t - d] : 0;
        __syncthreads();
        sums[t] = a + b;
        __syncthreads();
    }
    int run = sums[t] - s;
    if (full) {
        const int4* c4 = (const int4*)(cnt + lo);
        int4* rp4 = (int4*)(rowptr + lo);
        int4* cu4 = (int4*)(cursor + lo);
        for (int i = 0; i < chunk / 4; ++i) {
            int4 v = c4[i];
            int4 o;
            o.x = run; run += (v.x + 1) & ~1;
            o.y = run; run += (v.y + 1) & ~1;
            o.z = run; run += (v.z + 1) & ~1;
            o.w = run; run += (v.w + 1) & ~1;
            rp4[i] = o;
            cu4[i] = o;
        }
    } else {
        const int hi = (lo + chunk < N) ? lo + chunk : N;
        for (int i = lo; i < hi; ++i) {
            rowptr[i] = run;
            cursor[i] = run;
            run += (cnt[i] + 1) & ~1;
        }
    }
    if (t == SCAN_T - 1) rowptr[N] = sums[SCAN_T - 1];
}

__global__ __launch_bounds__(256) void spmm16_h2(
    const int* __restrict__ rowptr, const int2* __restrict__ ecv,
    const float* __restrict__ XW, const float* __restrict__ b1,
    const float* __restrict__ W2, float* __restrict__ h2, int N)
{
    const int gw = (int)((blockIdx.x * (size_t)blockDim.x + threadIdx.x) >> 6);
    if (gw >= N) return;
    const int lane = threadIdx.x & 63;
    const int j = lane & 15;
    const int w = lane >> 4;
    const int s = rowptr[gw], e = rowptr[gw + 1];

    float acc = 0.f;
    int k = s + w * 4;
    while (k + 4 <= e) {
        const int4* q = (const int4*)(ecv + k);
        int4 A = q[0], B = q[1];
        acc += __int_as_float(A.y) * XW[(size_t)A.x * HID + j];
        acc += __int_as_float(A.w) * XW[(size_t)A.z * HID + j];
        acc += __int_as_float(B.y) * XW[(size_t)B.x * HID + j];
        acc += __int_as_float(B.w) * XW[(size_t)B.z * HID + j];
        k += 16;
    }
    for (; k < e; ++k) {
        int2 a = ecv[k];
        acc += __int_as_float(a.y) * XW[(size_t)a.x * HID + j];
    }
    acc += __shfl_xor(acc, 16);
    acc += __shfl_xor(acc, 32);

    const float h = fmaxf(acc + b1[j], 0.f);
    float p[OUTC];
#pragma unroll
    for (int c = 0; c < OUTC; ++c) p[c] = h * W2[j * OUTC + c];
#pragma unroll
    for (int m = 1; m <= 8; m <<= 1)
#pragma unroll
        for (int c = 0; c < OUTC; ++c) p[c] += __shfl_xor(p[c], m);

    if (lane < 8) {
        float o = p[0];
        o = (lane == 1) ? p[1] : o;
        o = (lane == 2) ? p[2] : o;
        o = (lane == 3) ? p[3] : o;
        o = (lane == 4) ? p[4] : o;
        o = (lane == 5) ? p[5] : o;
        o = (lane == 6) ? p[6] : o;
        if (lane == 7) o = 0.f;
        h2[(size_t)gw * 8 + lane] = o;
    }
}

__global__ __launch_bounds__(256) void spmm7_lsm(
    const int* __restrict__ rowptr, const int2* __restrict__ ecv,
    const float* __restrict__ h2, const float* __restrict__ b2,
    float* __restrict__ out, int N)
{
    const int gw = (int)((blockIdx.x * (size_t)blockDim.x + threadIdx.x) >> 6);
    if (gw >= N) return;
    const int lane = threadIdx.x & 63;
    const int j = lane & 7;
    const int w = lane >> 3;
    const int s = rowptr[gw], e = rowptr[gw + 1];

    float acc = 0.f;
    int k = s + w * 4;
    while (k + 4 <= e) {
        const int4* q = (const int4*)(ecv + k);
        int4 A = q[0], B = q[1];
        acc += __int_as_float(A.y) * h2[(size_t)A.x * 8 + j];
        acc += __int_as_float(A.w) * h2[(size_t)A.z * 8 + j];
        acc += __int_as_float(B.y) * h2[(size_t)B.x * 8 + j];
        acc += __int_as_float(B.w) * h2[(size_t)B.z * 8 + j];
        k += 32;
    }
    for (; k < e; ++k) {
        int2 a = ecv[k];
        acc += __int_as_float(a.y) * h2[(size_t)a.x * 8 + j];
    }
    acc += __shfl_xor(acc, 8);
    acc += __shfl_xor(acc, 16);
    acc += __shfl_xor(acc, 32);

    const float bias = b2[(j < OUTC) ? j : 0];
    const float val  = acc + bias;
    float mx = (j < OUTC) ? val : -INFINITY;
    mx = fmaxf(mx, __shfl_xor(mx, 1));
    mx = fmaxf(mx, __shfl_xor(mx, 2));
    mx = fmaxf(mx, __shfl_xor(mx, 4));
    float ex = (j < OUTC) ? expf(val - mx) : 0.f;
    ex += __shfl_xor(ex, 1);
    ex += __shfl_xor(ex, 2);
    ex += __shfl_xor(ex, 4);
    if (lane < OUTC) out[(size_t)gw * OUTC + lane] = val - mx - logf(ex);
}

// ===========================================================================
// Tier-3 fallback (atomic)
// ===========================================================================
__global__ __launch_bounds__(256) void gcn_k2_spmm16_atomic(
    const int* __restrict__ arow, const int* __restrict__ acol,
    const float* __restrict__ aval, const float* __restrict__ XW,
    float* __restrict__ H, int E)
{
    int e = blockIdx.x * blockDim.x + threadIdx.x;
    if (e >= E) return;
    const int r = arow[e], c = acol[e];
    const float v = aval[e];
    const float4* src = (const float4*)(XW + (size_t)c * HID);
    float4 a = src[0], b = src[1], cc = src[2], d = src[3];
    float* dst = H + (size_t)r * HID;
    atomicAdd(dst + 0,  v * a.x);  atomicAdd(dst + 1,  v * a.y);
    atomicAdd(dst + 2,  v * a.z);  atomicAdd(dst + 3,  v * a.w);
    atomicAdd(dst + 4,  v * b.x);  atomicAdd(dst + 5,  v * b.y);
    atomicAdd(dst + 6,  v * b.z);  atomicAdd(dst + 7,  v * b.w);
    atomicAdd(dst + 8,  v * cc.x); atomicAdd(dst + 9,  v * cc.y);
    atomicAdd(dst + 10, v * cc.z); atomicAdd(dst + 11, v * cc.w);
    atomicAdd(dst + 12, v * d.x);  atomicAdd(dst + 13, v * d.y);
    atomicAdd(dst + 14, v * d.z);  atomicAdd(dst + 15, v * d.w);
}

__global__ __launch_bounds__(256) void gcn_k3_h2(
    const float* __restrict__ H, const float* __restrict__ b1,
    const float* __restrict__ W2, float* __restrict__ h2, int N)
{
    __shared__ float sW2[HID * OUTC];
    __shared__ float sb1[HID];
    if (threadIdx.x < HID * OUTC) sW2[threadIdx.x] = W2[threadIdx.x];
    if (threadIdx.x < HID)        sb1[threadIdx.x] = b1[threadIdx.x];
    __syncthreads();

    int row = blockIdx.x * blockDim.x + threadIdx.x;
    if (row >= N) return;

    const float4* hp = (const float4*)(H + (size_t)row * HID);
    float4 h0 = hp[0], h1 = hp[1], h2v = hp[2], h3 = hp[3];
    float h[16] = {h0.x, h0.y, h0.z, h0.w, h1.x, h1.y, h1.z, h1.w,
                   h2v.x, h2v.y, h2v.z, h2v.w, h3.x, h3.y, h3.z, h3.w};
#pragma unroll
    for (int i = 0; i < HID; ++i) {
        h[i] += sb1[i];
        h[i] = h[i] > 0.f ? h[i] : 0.f;
    }
    float o[8];
#pragma unroll
    for (int jj = 0; jj < OUTC; ++jj) {
        float sum = 0.f;
#pragma unroll
        for (int i = 0; i < HID; ++i) sum += h[i] * sW2[i * OUTC + jj];
        o[jj] = sum;
    }
    o[7] = 0.f;
    float4* op = (float4*)(h2 + (size_t)row * 8);
    op[0] = make_float4(o[0], o[1], o[2], o[3]);
    op[1] = make_float4(o[4], o[5], o[6], o[7]);
}

__global__ __launch_bounds__(256) void gcn_k4_spmm7_atomic(
    const int* __restrict__ arow, const int* __restrict__ acol,
    const float* __restrict__ aval, const float* __restrict__ h2,
    float* __restrict__ out, int E)
{
    int e = blockIdx.x * blockDim.x + threadIdx.x;
    if (e >= E) return;
    const int r = arow[e], c = acol[e];
    const float v = aval[e];
    const float* src = h2 + (size_t)c * 8;
    float* dst = out + (size_t)r * OUTC;
#pragma unroll
    for (int jj = 0; jj < OUTC; ++jj) atomicAdd(dst + jj, v * src[jj]);
}

__global__ __launch_bounds__(256) void gcn_k5_lsm(
    float* __restrict__ out, const float* __restrict__ b2, int N)
{
    int row = blockIdx.x * blockDim.x + threadIdx.x;
    if (row >= N) return;
    float* p = out + (size_t)row * OUTC;
    float v[OUTC];
#pragma unroll
    for (int jj = 0; jj < OUTC; ++jj) v[jj] = p[jj] + b2[jj];
    float m = v[0];
#pragma unroll
    for (int jj = 1; jj < OUTC; ++jj) m = fmaxf(m, v[jj]);
    float s = 0.f;
#pragma unroll
    for (int jj = 0; jj < OUTC; ++jj) s += expf(v[jj] - m);
    const float ls = logf(s);
#pragma unroll
    for (int jj = 0; jj < OUTC; ++jj) p[jj] = v[jj] - m - ls;
}

// ---------------------------------------------------------------------------
extern "C" void kernel_launch(void* const* d_in, const int* in_sizes, int n_in,
                              void* d_out, int out_size, void* d_ws, size_t ws_size,
                              hipStream_t stream)
{
    const float* x    = (const float*)d_in[0];
    const int*   arow = (const int*)d_in[1];
    const int*   acol = (const int*)d_in[2];
    const float* aval = (const float*)d_in[3];
    const float* W1   = (const float*)d_in[4];
    const float* b1   = (const float*)d_in[5];
    const float* W2   = (const float*)d_in[6];
    const float* b2   = (const float*)d_in[7];
    float* out = (float*)d_out;

    const int N = in_sizes[0] / IN_F;
    const int E = in_sizes[1];

    const int Np4 = (N + 3) & ~3;
    const int eb  = (E + 255) / 256;
    const int nb  = (N + 255) / 256;
    const int k1b = (N + K1_ROWS_B - 1) / K1_ROWS_B;
    const int nbuk = (N + RPB - 1) / RPB;
    const int scb1 = imin(384, k1b / 4);

    // ---- tier-1: bucket partition -> repack -> wave-per-row SpMM ----
    {
        char* wsp = (char*)d_ws;
        int2*  buckets = (int2*)wsp;  wsp += (size_t)nbuk * BCAP * 8;
        float* XW      = (float*)wsp; wsp += (size_t)N * HID * 4;
        float* h2      = (float*)wsp; wsp += (size_t)N * 8 * 4;
        int*   ovf     = (int*)wsp;   wsp += (size_t)OVF_CAP * 12;
        int*   rowptrB = (int*)wsp;   wsp += (size_t)nbuk * (RPB + 1) * 4;
        char*  zbase   = wsp;
        int*   cursor  = (int*)wsp;   wsp += (size_t)((nbuk + 3) & ~3) * 4;
        float* Hx      = (float*)wsp; wsp += (size_t)N * HID * 4;
        float* Ox      = (float*)wsp; wsp += (size_t)N * 8 * 4;
        int*   ovfc    = (int*)wsp;   wsp += 16;
        const size_t need1 = (size_t)(wsp - (char*)d_ws);

        if (ws_size >= need1 && scb1 >= 1 && N <= (1 << 17) &&
            nbuk <= K1_LDS_FLOATS) {
            const size_t zbytes = (size_t)(wsp - zbase);
            const int n4z = (int)(zbytes / 16);
            zero_i32<<<(n4z + 255) / 256, 256, 0, stream>>>((int4*)zbase, n4z);

            k1_partition<<<k1b + scb1, K1_THREADS, 0, stream>>>(
                x, W1, XW, N, k1b, arow, acol, aval, cursor, buckets,
                ovf, ovfc, E, nbuk, scb1);
            bucket_repack<<<nbuk, 512, 0, stream>>>(
                cursor, buckets, rowptrB, ovf, ovfc, nbuk);
            ovf_apply16<<<128, 256, 0, stream>>>(ovf, ovfc, XW, Hx);
            spmm16B<<<(N + 3) / 4, 256, 0, stream>>>(
                rowptrB, buckets, XW, Hx, b1, W2, h2, N);
            ovf_apply7<<<128, 256, 0, stream>>>(ovf, ovfc, h2, Ox);
            spmm7B<<<(N + 3) / 4, 256, 0, stream>>>(
                rowptrB, buckets, h2, Ox, b2, out, N);
            return;
        }
    }

    // ---- tier-2: CSR path ----
    {
        const int EPAD = E + N + 8;
        char* wsp = (char*)d_ws;
        int2*  ecv    = (int2*)wsp;   wsp += (size_t)EPAD * 8;
        int*   cnt    = (int*)wsp;    wsp += (size_t)Np4 * 4;
        int*   cursor = (int*)wsp;    wsp += (size_t)Np4 * 4;
        int*   rowptr = (int*)wsp;    wsp += (size_t)(Np4 + 4) * 4;
        float* XW     = (float*)wsp;  wsp += (size_t)N * HID * 4;
        float* h2     = (float*)wsp;  wsp += (size_t)N * 8 * 4;
        const size_t need2 = (size_t)(wsp - (char*)d_ws);

        if (ws_size >= need2) {
            const size_t zbytes = (size_t)EPAD * 8 + (size_t)Np4 * 4;
            const int n4z = (int)((zbytes + 15) / 16);
            zero_i32<<<(n4z + 255) / 256, 256, 0, stream>>>((int4*)d_ws, n4z);

            const int half1 = (k1b + 1) / 2;
            const int half2 = k1b - half1;
            const int histB = imin(384, half1 / 2);
            const int scb   = imin(384, half2 / 2);

            if (histB >= 1 && scb >= 1) {
                k1_hist_fused<<<half1 + histB, K1_THREADS, 0, stream>>>(
                    x, W1, XW, N, half1, arow, cnt, E, histB);
                csr_scan<<<1, SCAN_T, 0, stream>>>(cnt, rowptr, cursor, N);
                k1_scatter_fused<<<half2 + scb, K1_THREADS, 0, stream>>>(
                    x, W1, XW, N, half1, half2, arow, acol, aval, cursor, ecv, E, scb);
            } else {
                csr_hist<<<eb, 256, 0, stream>>>(arow, cnt, E);
                csr_scan<<<1, SCAN_T, 0, stream>>>(cnt, rowptr, cursor, N);
                csr_scatter<<<eb, 256, 0, stream>>>(arow, acol, aval, cursor, ecv, E);
                gcn_k1_xw<<<k1b, K1_THREADS, 0, stream>>>(x, W1, XW, N);
            }

            spmm16_h2<<<(N + 3) / 4, 256, 0, stream>>>(rowptr, ecv, XW, b1, W2, h2, N);
            spmm7_lsm<<<(N + 3) / 4, 256, 0, stream>>>(rowptr, ecv, h2, b2, out, N);
            return;
        }
    }

    // ---- tier-3: atomic fallback ----
    {
        float* XWf = (float*)d_ws;
        float* Hf  = XWf + (size_t)N * HID;
        float* h2f = XWf;
        const int hz4 = (int)(((size_t)N * HID) / 4);
        zero_i32<<<(hz4 + 255) / 256, 256, 0, stream>>>((int4*)Hf, hz4);
        (void)hipMemsetAsync(out, 0, (size_t)N * OUTC * sizeof(float), stream);
        gcn_k1_xw<<<k1b, K1_THREADS, 0, stream>>>(x, W1, XWf, N);
        gcn_k2_spmm16_atomic<<<eb, 256, 0, stream>>>(arow, acol, aval, XWf, Hf, E);
        gcn_k3_h2<<<nb, 256, 0, stream>>>(Hf, b1, W2, h2f, N);
        gcn_k4_spmm7_atomic<<<eb, 256, 0, stream>>>(arow, acol, aval, h2f, out, E);
        gcn_k5_lsm<<<nb, 256, 0, stream>>>(out, b2, N);
    }
}

// Round 17
// 378.050 us; speedup vs baseline: 3.3680x; 3.3680x over previous
//
#include <hip/hip_runtime.h>
#include <math.h>

#define IN_F 1433
#define HID  16
#define OUTC 7
#define SCAN_T 1024

// K1 geometry (v7: float4 x-loads + LDS W1, two-phase KA=768) — round-15 bank
#define K1_THREADS 512
#define K1_ROWS_W  8
#define K1_ROWS_B  64
#define KA         768
#define LDSW       17
#define K1_LDS_FLOATS (KA * LDSW)   // 52224 B

// bucket geometry
#define RPB      128               // rows per bucket (r_local: 7 bits)
#define BCAP     4480              // bucket capacity
#define PCH      2048              // partition chunk (512 thr x 4 edges)
#define OVF_CAP  131072            // spill capacity

typedef float f4_t __attribute__((ext_vector_type(4)));
typedef f4_t uf4 __attribute__((aligned(4)));

__host__ __device__ __forceinline__ int imin(int a, int b) { return a < b ? a : b; }

// ---------------------------------------------------------------------------
__global__ __launch_bounds__(256) void zero_i32(int4* __restrict__ p, int n4)
{
    int i = blockIdx.x * blockDim.x + threadIdx.x;
    if (i < n4) p[i] = make_int4(0, 0, 0, 0);
}

// ---------------------------------------------------------------------------
// K1 v7 body (proven rounds 13-15; ~84 VGPR, 3 blocks/CU — local optimum)
// ---------------------------------------------------------------------------
__device__ __forceinline__ void k1_body(
    const float* __restrict__ x, const float* __restrict__ W1,
    float* __restrict__ XW, int N, int vbid, float* sW)
{
    const int wave = threadIdx.x >> 6;
    const int lane = threadIdx.x & 63;
    const int ks   = lane & 15;
    const int j4   = lane >> 4;
    const int row0 = vbid * K1_ROWS_B + wave * K1_ROWS_W;

    int xoff[K1_ROWS_W];
#pragma unroll
    for (int r = 0; r < K1_ROWS_W; ++r) {
        int row = row0 + r;
        if (row > N - 1) row = N - 1;
        if (row < 0) row = 0;
        xoff[r] = row * IN_F;
    }

    float acc[K1_ROWS_W][4];
#pragma unroll
    for (int r = 0; r < K1_ROWS_W; ++r)
#pragma unroll
        for (int jj = 0; jj < 4; ++jj) acc[r][jj] = 0.f;

#pragma unroll 1
    for (int p = 0; p < 2; ++p) {
        const int pbase = p ? KA : 0;
        const int pk    = p ? (IN_F - KA) : KA;
        if (p) __syncthreads();
        for (int f = threadIdx.x; f < pk * HID; f += K1_THREADS)
            sW[(f >> 4) * LDSW + (f & 15)] = W1[pbase * HID + f];
        __syncthreads();

        const int nfull = pk >> 6;
#pragma unroll 1
        for (int c = 0; c < nfull; ++c) {
            const int kb = c * 64 + ks * 4;
            uf4 xq[K1_ROWS_W];
#pragma unroll
            for (int r = 0; r < K1_ROWS_W; ++r)
                xq[r] = *(const uf4*)(x + (size_t)xoff[r] + pbase + kb);
            float w[4][4];
#pragma unroll
            for (int kk = 0; kk < 4; ++kk) {
                const float* wr = sW + (size_t)(kb + kk) * LDSW + j4 * 4;
                w[kk][0] = wr[0]; w[kk][1] = wr[1];
                w[kk][2] = wr[2]; w[kk][3] = wr[3];
            }
#pragma unroll
            for (int kk = 0; kk < 4; ++kk)
#pragma unroll
                for (int r = 0; r < K1_ROWS_W; ++r) {
                    const float xv = xq[r][kk];
                    acc[r][0] += xv * w[kk][0];
                    acc[r][1] += xv * w[kk][1];
                    acc[r][2] += xv * w[kk][2];
                    acc[r][3] += xv * w[kk][3];
                }
        }

        const int tb = nfull * 64 + ks * 4;
        if (tb < pk + 3 && (pk & 63)) {
#pragma unroll
            for (int kk = 0; kk < 4; ++kk) {
                const int kloc = tb + kk;
                const bool ok = (kloc < pk);
                const float* wr = sW + (size_t)kloc * LDSW + j4 * 4;
                float w0 = wr[0], w1 = wr[1], w2 = wr[2], w3 = wr[3];
#pragma unroll
                for (int r = 0; r < K1_ROWS_W; ++r) {
                    const float xv = ok ? x[(size_t)xoff[r] + pbase + kloc] : 0.f;
                    acc[r][0] += xv * w0;
                    acc[r][1] += xv * w1;
                    acc[r][2] += xv * w2;
                    acc[r][3] += xv * w3;
                }
            }
        }
    }

#pragma unroll
    for (int m = 1; m <= 8; m <<= 1)
#pragma unroll
        for (int r = 0; r < K1_ROWS_W; ++r)
#pragma unroll
            for (int jj = 0; jj < 4; ++jj)
                acc[r][jj] += __shfl_xor(acc[r][jj], m);

    if (ks == 0) {
#pragma unroll
        for (int r = 0; r < K1_ROWS_W; ++r) {
            const int row = row0 + r;
            if (row >= 0 && row < N) {
                float4 o = make_float4(acc[r][0], acc[r][1], acc[r][2], acc[r][3]);
                *(float4*)(XW + (size_t)row * HID + j4 * 4) = o;
            }
        }
    }
}

// ---------------------------------------------------------------------------
// partition_body (proven round 14-15)
// ---------------------------------------------------------------------------
__device__ __forceinline__ void partition_body(
    const int* __restrict__ arow, const int* __restrict__ acol,
    const float* __restrict__ aval, int* __restrict__ cursor,
    int2* __restrict__ buckets, int* __restrict__ ovf, int* __restrict__ ovfc,
    int E, int nbuk, int sb, int nsb, int* hist)
{
    const int nch = (E + PCH - 1) / PCH;
    for (int ch = sb; ch < nch; ch += nsb) {
        const int e0 = ch * PCH;
        const int e1 = imin(e0 + PCH, E);
        for (int b = threadIdx.x; b < nbuk; b += K1_THREADS) hist[b] = 0;
        __syncthreads();

        int rr[4], cc[4]; float vv[4];
        int nl = 0;
        const int base = e0 + threadIdx.x * 4;
        if (base + 3 < e1) {
            int4 r4 = *(const int4*)(arow + base);
            int4 c4 = *(const int4*)(acol + base);
            float4 v4 = *(const float4*)(aval + base);
            rr[0]=r4.x; rr[1]=r4.y; rr[2]=r4.z; rr[3]=r4.w;
            cc[0]=c4.x; cc[1]=c4.y; cc[2]=c4.z; cc[3]=c4.w;
            vv[0]=v4.x; vv[1]=v4.y; vv[2]=v4.z; vv[3]=v4.w;
            nl = 4;
        } else {
            for (int i = base; i < e1 && nl < 4; ++i) {
                rr[nl] = arow[i]; cc[nl] = acol[i]; vv[nl] = aval[i];
                ++nl;
            }
        }
        for (int u = 0; u < nl; ++u) atomicAdd(&hist[rr[u] >> 7], 1);
        __syncthreads();

        for (int b = threadIdx.x; b < nbuk; b += K1_THREADS) {
            const int h = hist[b];
            hist[b] = (h > 0) ? atomicAdd(&cursor[b], h) : 0;
        }
        __syncthreads();

        for (int u = 0; u < nl; ++u) {
            const int b = rr[u] >> 7;
            const int pos = atomicAdd(&hist[b], 1);
            if (pos < BCAP) {
                buckets[(size_t)b * BCAP + pos] =
                    make_int2(((rr[u] & (RPB - 1)) << 17) | cc[u],
                              __float_as_int(vv[u]));
            } else {
                int op = atomicAdd(ovfc, 1);
                if (op < OVF_CAP) {
                    ovf[3 * op]     = rr[u];
                    ovf[3 * op + 1] = cc[u];
                    ovf[3 * op + 2] = __float_as_int(vv[u]);
                }
            }
        }
        __syncthreads();
    }
}

__global__ __launch_bounds__(K1_THREADS) void k1_partition(
    const float* __restrict__ x, const float* __restrict__ W1,
    float* __restrict__ XW, int N, int k1b,
    const int* __restrict__ arow, const int* __restrict__ acol,
    const float* __restrict__ aval, int* __restrict__ cursor,
    int2* __restrict__ buckets, int* __restrict__ ovf, int* __restrict__ ovfc,
    int E, int nbuk, int scb)
{
    __shared__ float sW[K1_LDS_FLOATS];
    const int bid = blockIdx.x;
    if ((bid % 4 == 3) && (bid / 4 < scb)) {
        partition_body(arow, acol, aval, cursor, buckets, ovf, ovfc,
                       E, nbuk, bid / 4, scb, (int*)sW);
        return;
    }
    const int k1_idx = bid - imin((bid + 1) / 4, scb);
    if (k1_idx >= k1b) return;
    k1_body(x, W1, XW, N, k1_idx, sW);
}

// ---------------------------------------------------------------------------
// bucket_repack (proven round 15)
// ---------------------------------------------------------------------------
__global__ __launch_bounds__(512) void bucket_repack(
    const int* __restrict__ cursor, int2* __restrict__ buckets,
    int* __restrict__ rowptrB, int* __restrict__ ovf, int* __restrict__ ovfc,
    int nbuk)
{
    __shared__ int2 ebuf[BCAP];
    __shared__ int rcnt[RPB];
    __shared__ int rcur[RPB];
    __shared__ int rbase[RPB + 1];
    const int b = blockIdx.x;
    const int cnt_b = imin(cursor[b], BCAP);
    int2* src = buckets + (size_t)b * BCAP;

    for (int r = threadIdx.x; r < RPB; r += 512) { rcnt[r] = 0; rcur[r] = 0; }
    __syncthreads();

    for (int i = threadIdx.x; i < cnt_b; i += 512)
        atomicAdd(&rcnt[src[i].x >> 17], 1);
    __syncthreads();

    if (threadIdx.x == 0) {
        int run = 0;
        for (int r = 0; r < RPB; ++r) {
            rbase[r] = run;
            run += (rcnt[r] + 1) & ~1;
        }
        rbase[RPB] = run;
    }
    __syncthreads();

    for (int r = threadIdx.x; r < RPB; r += 512) {
        if (rcnt[r] & 1) {
            const int pp = rbase[r] + rcnt[r];
            if (pp < BCAP) ebuf[pp] = make_int2(0, 0);
        }
    }
    __syncthreads();

    for (int i = threadIdx.x; i < cnt_b; i += 512) {
        const int2 ed = src[i];
        const int rl = ed.x >> 17;
        const int pos = rbase[rl] + atomicAdd(&rcur[rl], 1);
        if (pos < BCAP) {
            ebuf[pos] = make_int2(ed.x & 0x1FFFF, ed.y);
        } else {
            int op = atomicAdd(ovfc, 1);
            if (op < OVF_CAP) {
                ovf[3 * op]     = b * RPB + rl;
                ovf[3 * op + 1] = ed.x & 0x1FFFF;
                ovf[3 * op + 2] = ed.y;
            }
        }
    }
    __syncthreads();

    const int total = imin(rbase[RPB], BCAP);
    for (int i = threadIdx.x; i < total; i += 512) src[i] = ebuf[i];
    for (int r = threadIdx.x; r < RPB; r += 512)
        rowptrB[b * (RPB + 1) + r] = imin(rbase[r], BCAP);
    if (threadIdx.x == 0)
        rowptrB[b * (RPB + 1) + RPB] = total;
}

// ---------------------------------------------------------------------------
// Overflow apply
// ---------------------------------------------------------------------------
__global__ __launch_bounds__(256) void ovf_apply16(
    const int* __restrict__ ovf, const int* __restrict__ ovfc,
    const float* __restrict__ XW, float* __restrict__ Hx)
{
    const int n = imin(ovfc[0], OVF_CAP);
    const int tid = blockIdx.x * blockDim.x + threadIdx.x;
    const int stride = gridDim.x * blockDim.x;
    for (int i = tid; i < n; i += stride) {
        const int r = ovf[3 * i], c = ovf[3 * i + 1];
        const float v = __int_as_float(ovf[3 * i + 2]);
        const float* src = XW + (size_t)c * HID;
        float* dst = Hx + (size_t)r * HID;
#pragma unroll
        for (int j = 0; j < HID; ++j) atomicAdd(dst + j, v * src[j]);
    }
}

__global__ __launch_bounds__(256) void ovf_apply7(
    const int* __restrict__ ovf, const int* __restrict__ ovfc,
    const float* __restrict__ h2, float* __restrict__ Ox)
{
    const int n = imin(ovfc[0], OVF_CAP);
    const int tid = blockIdx.x * blockDim.x + threadIdx.x;
    const int stride = gridDim.x * blockDim.x;
    for (int i = tid; i < n; i += stride) {
        const int r = ovf[3 * i], c = ovf[3 * i + 1];
        const float v = __int_as_float(ovf[3 * i + 2]);
        const float* src = h2 + (size_t)c * 8;
        float* dst = Ox + (size_t)r * 8;
#pragma unroll
        for (int j = 0; j < OUTC; ++j) atomicAdd(dst + j, v * src[j]);
    }
}

// ---------------------------------------------------------------------------
// spmm16B: wave-per-row over repacked buckets (+Hx)  [proven round 15]
// ---------------------------------------------------------------------------
__global__ __launch_bounds__(256) void spmm16B(
    const int* __restrict__ rowptrB, const int2* __restrict__ buckets,
    const float* __restrict__ XW, const float* __restrict__ Hx,
    const float* __restrict__ b1, const float* __restrict__ W2,
    float* __restrict__ h2, int N)
{
    const int gw = (int)((blockIdx.x * (size_t)blockDim.x + threadIdx.x) >> 6);
    if (gw >= N) return;
    const int lane = threadIdx.x & 63;
    const int j = lane & 15;
    const int w = lane >> 4;
    const int b  = gw >> 7;
    const int rl = gw & (RPB - 1);
    const int rs = rowptrB[b * (RPB + 1) + rl];
    const int re = rowptrB[b * (RPB + 1) + rl + 1];
    const int2* base = buckets + (size_t)b * BCAP;

    float acc = 0.f;
    int k = rs + w * 4;
    while (k + 4 <= re) {
        const int4* q = (const int4*)(base + k);
        int4 A = q[0], B = q[1];
        acc += __int_as_float(A.y) * XW[(size_t)A.x * HID + j];
        acc += __int_as_float(A.w) * XW[(size_t)A.z * HID + j];
        acc += __int_as_float(B.y) * XW[(size_t)B.x * HID + j];
        acc += __int_as_float(B.w) * XW[(size_t)B.z * HID + j];
        k += 16;
    }
    for (; k < re; ++k) {
        int2 a = base[k];
        acc += __int_as_float(a.y) * XW[(size_t)a.x * HID + j];
    }
    acc += __shfl_xor(acc, 16);
    acc += __shfl_xor(acc, 32);
    acc += Hx[(size_t)gw * HID + j];

    const float h = fmaxf(acc + b1[j], 0.f);
    float p[OUTC];
#pragma unroll
    for (int c = 0; c < OUTC; ++c) p[c] = h * W2[j * OUTC + c];
#pragma unroll
    for (int m = 1; m <= 8; m <<= 1)
#pragma unroll
        for (int c = 0; c < OUTC; ++c) p[c] += __shfl_xor(p[c], m);

    if (lane < 8) {
        float o = p[0];
        o = (lane == 1) ? p[1] : o;
        o = (lane == 2) ? p[2] : o;
        o = (lane == 3) ? p[3] : o;
        o = (lane == 4) ? p[4] : o;
        o = (lane == 5) ? p[5] : o;
        o = (lane == 6) ? p[6] : o;
        if (lane == 7) o = 0.f;
        h2[(size_t)gw * 8 + lane] = o;
    }
}

// ---------------------------------------------------------------------------
// spmm7B: wave-per-row + fused log_softmax (+Ox)  [proven round 15]
// ---------------------------------------------------------------------------
__global__ __launch_bounds__(256) void spmm7B(
    const int* __restrict__ rowptrB, const int2* __restrict__ buckets,
    const float* __restrict__ h2, const float* __restrict__ Ox,
    const float* __restrict__ b2, float* __restrict__ out, int N)
{
    const int gw = (int)((blockIdx.x * (size_t)blockDim.x + threadIdx.x) >> 6);
    if (gw >= N) return;
    const int lane = threadIdx.x & 63;
    const int j = lane & 7;
    const int w = lane >> 3;
    const int b  = gw >> 7;
    const int rl = gw & (RPB - 1);
    const int rs = rowptrB[b * (RPB + 1) + rl];
    const int re = rowptrB[b * (RPB + 1) + rl + 1];
    const int2* base = buckets + (size_t)b * BCAP;

    float acc = 0.f;
    int k = rs + w * 4;
    while (k + 4 <= re) {
        const int4* q = (const int4*)(base + k);
        int4 A = q[0], B = q[1];
        acc += __int_as_float(A.y) * h2[(size_t)A.x * 8 + j];
        acc += __int_as_float(A.w) * h2[(size_t)A.z * 8 + j];
        acc += __int_as_float(B.y) * h2[(size_t)B.x * 8 + j];
        acc += __int_as_float(B.w) * h2[(size_t)B.z * 8 + j];
        k += 32;
    }
    for (; k < re; ++k) {
        int2 a = base[k];
        acc += __int_as_float(a.y) * h2[(size_t)a.x * 8 + j];
    }
    acc += __shfl_xor(acc, 8);
    acc += __shfl_xor(acc, 16);
    acc += __shfl_xor(acc, 32);
    acc += Ox[(size_t)gw * 8 + j];

    const float bias = b2[(j < OUTC) ? j : 0];
    const float val  = acc + bias;
    float mx = (j < OUTC) ? val : -INFINITY;
    mx = fmaxf(mx, __shfl_xor(mx, 1));
    mx = fmaxf(mx, __shfl_xor(mx, 2));
    mx = fmaxf(mx, __shfl_xor(mx, 4));
    float ex = (j < OUTC) ? expf(val - mx) : 0.f;
    ex += __shfl_xor(ex, 1);
    ex += __shfl_xor(ex, 2);
    ex += __shfl_xor(ex, 4);
    if (lane < OUTC) out[(size_t)gw * OUTC + lane] = val - mx - logf(ex);
}

// ===========================================================================
// Tier-2: CSR path
// ===========================================================================
__device__ __forceinline__ void hist_body(
    const int* __restrict__ arow, int* __restrict__ cnt, int E, int hb, int nhb)
{
    const int tid = hb * K1_THREADS + threadIdx.x;
    const int stride = nhb * K1_THREADS;
    const int E4 = E >> 2;
    const int4* a4 = (const int4*)arow;
    for (int v = tid; v < E4; v += stride) {
        int4 r = a4[v];
        atomicAdd(&cnt[r.x], 1);
        atomicAdd(&cnt[r.y], 1);
        atomicAdd(&cnt[r.z], 1);
        atomicAdd(&cnt[r.w], 1);
    }
    for (int v = E4 * 4 + tid; v < E; v += stride) atomicAdd(&cnt[arow[v]], 1);
}

__device__ __forceinline__ void scatter_body(
    const int* __restrict__ arow, const int* __restrict__ acol,
    const float* __restrict__ aval, int* __restrict__ cursor,
    int2* __restrict__ ecv, int E, int sb, int nsb)
{
    const int tid = sb * K1_THREADS + threadIdx.x;
    const int stride = nsb * K1_THREADS;
    const int E4 = E >> 2;
    const int4*   ar4 = (const int4*)arow;
    const int4*   ac4 = (const int4*)acol;
    const float4* av4 = (const float4*)aval;
    for (int v = tid; v < E4; v += stride) {
        int4 r = ar4[v];
        int4 c = ac4[v];
        float4 val = av4[v];
        int p0 = atomicAdd(&cursor[r.x], 1);
        int p1 = atomicAdd(&cursor[r.y], 1);
        int p2 = atomicAdd(&cursor[r.z], 1);
        int p3 = atomicAdd(&cursor[r.w], 1);
        ecv[p0] = make_int2(c.x, __float_as_int(val.x));
        ecv[p1] = make_int2(c.y, __float_as_int(val.y));
        ecv[p2] = make_int2(c.z, __float_as_int(val.z));
        ecv[p3] = make_int2(c.w, __float_as_int(val.w));
    }
    for (int v = E4 * 4 + tid; v < E; v += stride) {
        int pos = atomicAdd(&cursor[arow[v]], 1);
        ecv[pos] = make_int2(acol[v], __float_as_int(aval[v]));
    }
}

__global__ __launch_bounds__(K1_THREADS) void k1_hist_fused(
    const float* __restrict__ x, const float* __restrict__ W1,
    float* __restrict__ XW, int N, int half1,
    const int* __restrict__ arow, int* __restrict__ cnt, int E, int histB)
{
    __shared__ float sW[K1_LDS_FLOATS];
    const int bid = blockIdx.x;
    if ((bid % 3 == 2) && (bid / 3 < histB)) {
        hist_body(arow, cnt, E, bid / 3, histB);
        return;
    }
    const int k1_idx = bid - imin((bid + 1) / 3, histB);
    if (k1_idx >= half1) return;
    k1_body(x, W1, XW, N, k1_idx, sW);
}

__global__ __launch_bounds__(K1_THREADS) void k1_scatter_fused(
    const float* __restrict__ x, const float* __restrict__ W1,
    float* __restrict__ XW, int N, int half1, int half2,
    const int* __restrict__ arow, const int* __restrict__ acol,
    const float* __restrict__ aval, int* __restrict__ cursor,
    int2* __restrict__ ecv, int E, int scb)
{
    __shared__ float sW[K1_LDS_FLOATS];
    const int bid = blockIdx.x;
    if ((bid % 3 == 2) && (bid / 3 < scb)) {
        scatter_body(arow, acol, aval, cursor, ecv, E, bid / 3, scb);
        return;
    }
    const int k1_idx = bid - imin((bid + 1) / 3, scb) + half1;
    if (k1_idx >= half1 + half2) return;
    k1_body(x, W1, XW, N, k1_idx, sW);
}

__global__ __launch_bounds__(K1_THREADS) void gcn_k1_xw(
    const float* __restrict__ x, const float* __restrict__ W1,
    float* __restrict__ XW, int N)
{
    __shared__ float sW[K1_LDS_FLOATS];
    k1_body(x, W1, XW, N, blockIdx.x, sW);
}

__global__ __launch_bounds__(256) void csr_hist(
    const int* __restrict__ arow, int* __restrict__ cnt, int E)
{
    int e = blockIdx.x * blockDim.x + threadIdx.x;
    if (e < E) atomicAdd(&cnt[arow[e]], 1);
}

__global__ __launch_bounds__(256) void csr_scatter(
    const int* __restrict__ arow, const int* __restrict__ acol,
    const float* __restrict__ aval, int* __restrict__ cursor,
    int2* __restrict__ ecv, int E)
{
    int e = blockIdx.x * blockDim.x + threadIdx.x;
    if (e >= E) return;
    int pos = atomicAdd(&cursor[arow[e]], 1);
    ecv[pos] = make_int2(acol[e], __float_as_int(aval[e]));
}

__global__ __launch_bounds__(SCAN_T) void csr_scan(
    const int* __restrict__ cnt, int* __restrict__ rowptr,
    int* __restrict__ cursor, int N)
{
    __shared__ int sums[SCAN_T];
    const int t = threadIdx.x;
    const int chunk = (((N + SCAN_T - 1) / SCAN_T) + 3) & ~3;
    const int lo = t * chunk;
    int s = 0;
    const bool full = (lo + chunk <= N);
    if (full) {
        const int4* c4 = (const int4*)(cnt + lo);
#pragma unroll 4
        for (int i = 0; i < chunk / 4; ++i) {
            int4 v = c4[i];
            s += ((v.x + 1) & ~1) + ((v.y + 1) & ~1)
               + ((v.z + 1) & ~1) + ((v.w + 1) & ~1);
        }
    } else {
        const int hi = (lo + chunk < N) ? lo + chunk : N;
        for (int i = lo; i < hi; ++i) s += (cnt[i] + 1) & ~1;
    }
    sums[t] = s;
    __syncthreads();
    for (int d = 1; d < SCAN_T; d <<= 1) {
        int a = sums[t];
        int b = (t >= d) ? sums[t - d] : 0;
        __syncthreads();
        sums[t] = a + b;
        __syncthreads();
    }
    int run = sums[t] - s;
    if (full) {
        const int4* c4 = (const int4*)(cnt + lo);
        int4* rp4 = (int4*)(rowptr + lo);
        int4* cu4 = (int4*)(cursor + lo);
        for (int i = 0; i < chunk / 4; ++i) {
            int4 v = c4[i];
            int4 o;
            o.x = run; run += (v.x + 1) & ~1;
            o.y = run; run += (v.y + 1) & ~1;
            o.z = run; run += (v.z + 1) & ~1;
            o.w = run; run += (v.w + 1) & ~1;
            rp4[i] = o;
            cu4[i] = o;
        }
    } else {
        const int hi = (lo + chunk < N) ? lo + chunk : N;
        for (int i = lo; i < hi; ++i) {
            rowptr[i] = run;
            cursor[i] = run;
            run += (cnt[i] + 1) & ~1;
        }
    }
    if (t == SCAN_T - 1) rowptr[N] = sums[SCAN_T - 1];
}

__global__ __launch_bounds__(256) void spmm16_h2(
    const int* __restrict__ rowptr, const int2* __restrict__ ecv,
    const float* __restrict__ XW, const float* __restrict__ b1,
    const float* __restrict__ W2, float* __restrict__ h2, int N)
{
    const int gw = (int)((blockIdx.x * (size_t)blockDim.x + threadIdx.x) >> 6);
    if (gw >= N) return;
    const int lane = threadIdx.x & 63;
    const int j = lane & 15;
    const int w = lane >> 4;
    const int s = rowptr[gw], e = rowptr[gw + 1];

    float acc = 0.f;
    int k = s + w * 4;
    while (k + 4 <= e) {
        const int4* q = (const int4*)(ecv + k);
        int4 A = q[0], B = q[1];
        acc += __int_as_float(A.y) * XW[(size_t)A.x * HID + j];
        acc += __int_as_float(A.w) * XW[(size_t)A.z * HID + j];
        acc += __int_as_float(B.y) * XW[(size_t)B.x * HID + j];
        acc += __int_as_float(B.w) * XW[(size_t)B.z * HID + j];
        k += 16;
    }
    for (; k < e; ++k) {
        int2 a = ecv[k];
        acc += __int_as_float(a.y) * XW[(size_t)a.x * HID + j];
    }
    acc += __shfl_xor(acc, 16);
    acc += __shfl_xor(acc, 32);

    const float h = fmaxf(acc + b1[j], 0.f);
    float p[OUTC];
#pragma unroll
    for (int c = 0; c < OUTC; ++c) p[c] = h * W2[j * OUTC + c];
#pragma unroll
    for (int m = 1; m <= 8; m <<= 1)
#pragma unroll
        for (int c = 0; c < OUTC; ++c) p[c] += __shfl_xor(p[c], m);

    if (lane < 8) {
        float o = p[0];
        o = (lane == 1) ? p[1] : o;
        o = (lane == 2) ? p[2] : o;
        o = (lane == 3) ? p[3] : o;
        o = (lane == 4) ? p[4] : o;
        o = (lane == 5) ? p[5] : o;
        o = (lane == 6) ? p[6] : o;
        if (lane == 7) o = 0.f;
        h2[(size_t)gw * 8 + lane] = o;
    }
}

__global__ __launch_bounds__(256) void spmm7_lsm(
    const int* __restrict__ rowptr, const int2* __restrict__ ecv,
    const float* __restrict__ h2, const float* __restrict__ b2,
    float* __restrict__ out, int N)
{
    const int gw = (int)((blockIdx.x * (size_t)blockDim.x + threadIdx.x) >> 6);
    if (gw >= N) return;
    const int lane = threadIdx.x & 63;
    const int j = lane & 7;
    const int w = lane >> 3;
    const int s = rowptr[gw], e = rowptr[gw + 1];

    float acc = 0.f;
    int k = s + w * 4;
    while (k + 4 <= e) {
        const int4* q = (const int4*)(ecv + k);
        int4 A = q[0], B = q[1];
        acc += __int_as_float(A.y) * h2[(size_t)A.x * 8 + j];
        acc += __int_as_float(A.w) * h2[(size_t)A.z * 8 + j];
        acc += __int_as_float(B.y) * h2[(size_t)B.x * 8 + j];
        acc += __int_as_float(B.w) * h2[(size_t)B.z * 8 + j];
        k += 32;
    }
    for (; k < e; ++k) {
        int2 a = ecv[k];
        acc += __int_as_float(a.y) * h2[(size_t)a.x * 8 + j];
    }
    acc += __shfl_xor(acc, 8);
    acc += __shfl_xor(acc, 16);
    acc += __shfl_xor(acc, 32);

    const float bias = b2[(j < OUTC) ? j : 0];
    const float val  = acc + bias;
    float mx = (j < OUTC) ? val : -INFINITY;
    mx = fmaxf(mx, __shfl_xor(mx, 1));
    mx = fmaxf(mx, __shfl_xor(mx, 2));
    mx = fmaxf(mx, __shfl_xor(mx, 4));
    float ex = (j < OUTC) ? expf(val - mx) : 0.f;
    ex += __shfl_xor(ex, 1);
    ex += __shfl_xor(ex, 2);
    ex += __shfl_xor(ex, 4);
    if (lane < OUTC) out[(size_t)gw * OUTC + lane] = val - mx - logf(ex);
}

// ===========================================================================
// Tier-3 fallback (atomic)
// ===========================================================================
__global__ __launch_bounds__(256) void gcn_k2_spmm16_atomic(
    const int* __restrict__ arow, const int* __restrict__ acol,
    const float* __restrict__ aval, const float* __restrict__ XW,
    float* __restrict__ H, int E)
{
    int e = blockIdx.x * blockDim.x + threadIdx.x;
    if (e >= E) return;
    const int r = arow[e], c = acol[e];
    const float v = aval[e];
    const float4* src = (const float4*)(XW + (size_t)c * HID);
    float4 a = src[0], b = src[1], cc = src[2], d = src[3];
    float* dst = H + (size_t)r * HID;
    atomicAdd(dst + 0,  v * a.x);  atomicAdd(dst + 1,  v * a.y);
    atomicAdd(dst + 2,  v * a.z);  atomicAdd(dst + 3,  v * a.w);
    atomicAdd(dst + 4,  v * b.x);  atomicAdd(dst + 5,  v * b.y);
    atomicAdd(dst + 6,  v * b.z);  atomicAdd(dst + 7,  v * b.w);
    atomicAdd(dst + 8,  v * cc.x); atomicAdd(dst + 9,  v * cc.y);
    atomicAdd(dst + 10, v * cc.z); atomicAdd(dst + 11, v * cc.w);
    atomicAdd(dst + 12, v * d.x);  atomicAdd(dst + 13, v * d.y);
    atomicAdd(dst + 14, v * d.z);  atomicAdd(dst + 15, v * d.w);
}

__global__ __launch_bounds__(256) void gcn_k3_h2(
    const float* __restrict__ H, const float* __restrict__ b1,
    const float* __restrict__ W2, float* __restrict__ h2, int N)
{
    __shared__ float sW2[HID * OUTC];
    __shared__ float sb1[HID];
    if (threadIdx.x < HID * OUTC) sW2[threadIdx.x] = W2[threadIdx.x];
    if (threadIdx.x < HID)        sb1[threadIdx.x] = b1[threadIdx.x];
    __syncthreads();

    int row = blockIdx.x * blockDim.x + threadIdx.x;
    if (row >= N) return;

    const float4* hp = (const float4*)(H + (size_t)row * HID);
    float4 h0 = hp[0], h1 = hp[1], h2v = hp[2], h3 = hp[3];
    float h[16] = {h0.x, h0.y, h0.z, h0.w, h1.x, h1.y, h1.z, h1.w,
                   h2v.x, h2v.y, h2v.z, h2v.w, h3.x, h3.y, h3.z, h3.w};
#pragma unroll
    for (int i = 0; i < HID; ++i) {
        h[i] += sb1[i];
        h[i] = h[i] > 0.f ? h[i] : 0.f;
    }
    float o[8];
#pragma unroll
    for (int jj = 0; jj < OUTC; ++jj) {
        float sum = 0.f;
#pragma unroll
        for (int i = 0; i < HID; ++i) sum += h[i] * sW2[i * OUTC + jj];
        o[jj] = sum;
    }
    o[7] = 0.f;
    float4* op = (float4*)(h2 + (size_t)row * 8);
    op[0] = make_float4(o[0], o[1], o[2], o[3]);
    op[1] = make_float4(o[4], o[5], o[6], o[7]);
}

__global__ __launch_bounds__(256) void gcn_k4_spmm7_atomic(
    const int* __restrict__ arow, const int* __restrict__ acol,
    const float* __restrict__ aval, const float* __restrict__ h2,
    float* __restrict__ out, int E)
{
    int e = blockIdx.x * blockDim.x + threadIdx.x;
    if (e >= E) return;
    const int r = arow[e], c = acol[e];
    const float v = aval[e];
    const float* src = h2 + (size_t)c * 8;
    float* dst = out + (size_t)r * OUTC;
#pragma unroll
    for (int jj = 0; jj < OUTC; ++jj) atomicAdd(dst + jj, v * src[jj]);
}

__global__ __launch_bounds__(256) void gcn_k5_lsm(
    float* __restrict__ out, const float* __restrict__ b2, int N)
{
    int row = blockIdx.x * blockDim.x + threadIdx.x;
    if (row >= N) return;
    float* p = out + (size_t)row * OUTC;
    float v[OUTC];
#pragma unroll
    for (int jj = 0; jj < OUTC; ++jj) v[jj] = p[jj] + b2[jj];
    float m = v[0];
#pragma unroll
    for (int jj = 1; jj < OUTC; ++jj) m = fmaxf(m, v[jj]);
    float s = 0.f;
#pragma unroll
    for (int jj = 0; jj < OUTC; ++jj) s += expf(v[jj] - m);
    const float ls = logf(s);
#pragma unroll
    for (int jj = 0; jj < OUTC; ++jj) p[jj] = v[jj] - m - ls;
}

// ---------------------------------------------------------------------------
extern "C" void kernel_launch(void* const* d_in, const int* in_sizes, int n_in,
                              void* d_out, int out_size, void* d_ws, size_t ws_size,
                              hipStream_t stream)
{
    const float* x    = (const float*)d_in[0];
    const int*   arow = (const int*)d_in[1];
    const int*   acol = (const int*)d_in[2];
    const float* aval = (const float*)d_in[3];
    const float* W1   = (const float*)d_in[4];
    const float* b1   = (const float*)d_in[5];
    const float* W2   = (const float*)d_in[6];
    const float* b2   = (const float*)d_in[7];
    float* out = (float*)d_out;

    const int N = in_sizes[0] / IN_F;
    const int E = in_sizes[1];

    const int Np4 = (N + 3) & ~3;
    const int eb  = (E + 255) / 256;
    const int nb  = (N + 255) / 256;
    const int k1b = (N + K1_ROWS_B - 1) / K1_ROWS_B;
    const int nbuk = (N + RPB - 1) / RPB;
    const int scb1 = imin(384, k1b / 4);

    // ---- tier-1: bucket partition -> repack -> wave-per-row SpMM ----
    {
        char* wsp = (char*)d_ws;
        int2*  buckets = (int2*)wsp;  wsp += (size_t)nbuk * BCAP * 8;
        float* XW      = (float*)wsp; wsp += (size_t)N * HID * 4;
        float* h2      = (float*)wsp; wsp += (size_t)N * 8 * 4;
        int*   ovf     = (int*)wsp;   wsp += (size_t)OVF_CAP * 12;
        int*   rowptrB = (int*)wsp;   wsp += (size_t)nbuk * (RPB + 1) * 4;
        char*  zbase   = wsp;
        int*   cursor  = (int*)wsp;   wsp += (size_t)((nbuk + 3) & ~3) * 4;
        float* Hx      = (float*)wsp; wsp += (size_t)N * HID * 4;
        float* Ox      = (float*)wsp; wsp += (size_t)N * 8 * 4;
        int*   ovfc    = (int*)wsp;   wsp += 16;
        const size_t need1 = (size_t)(wsp - (char*)d_ws);

        if (ws_size >= need1 && scb1 >= 1 && N <= (1 << 17) &&
            nbuk <= K1_LDS_FLOATS) {
            const size_t zbytes = (size_t)(wsp - zbase);
            const int n4z = (int)(zbytes / 16);
            zero_i32<<<(n4z + 255) / 256, 256, 0, stream>>>((int4*)zbase, n4z);

            k1_partition<<<k1b + scb1, K1_THREADS, 0, stream>>>(
                x, W1, XW, N, k1b, arow, acol, aval, cursor, buckets,
                ovf, ovfc, E, nbuk, scb1);
            bucket_repack<<<nbuk, 512, 0, stream>>>(
                cursor, buckets, rowptrB, ovf, ovfc, nbuk);
            ovf_apply16<<<128, 256, 0, stream>>>(ovf, ovfc, XW, Hx);
            spmm16B<<<(N + 3) / 4, 256, 0, stream>>>(
                rowptrB, buckets, XW, Hx, b1, W2, h2, N);
            ovf_apply7<<<128, 256, 0, stream>>>(ovf, ovfc, h2, Ox);
            spmm7B<<<(N + 3) / 4, 256, 0, stream>>>(
                rowptrB, buckets, h2, Ox, b2, out, N);
            return;
        }
    }

    // ---- tier-2: CSR path ----
    {
        const int EPAD = E + N + 8;
        char* wsp = (char*)d_ws;
        int2*  ecv    = (int2*)wsp;   wsp += (size_t)EPAD * 8;
        int*   cnt    = (int*)wsp;    wsp += (size_t)Np4 * 4;
        int*   cursor = (int*)wsp;    wsp += (size_t)Np4 * 4;
        int*   rowptr = (int*)wsp;    wsp += (size_t)(Np4 + 4) * 4;
        float* XW     = (float*)wsp;  wsp += (size_t)N * HID * 4;
        float* h2     = (float*)wsp;  wsp += (size_t)N * 8 * 4;
        const size_t need2 = (size_t)(wsp - (char*)d_ws);

        if (ws_size >= need2) {
            const size_t zbytes = (size_t)EPAD * 8 + (size_t)Np4 * 4;
            const int n4z = (int)((zbytes + 15) / 16);
            zero_i32<<<(n4z + 255) / 256, 256, 0, stream>>>((int4*)d_ws, n4z);

            const int half1 = (k1b + 1) / 2;
            const int half2 = k1b - half1;
            const int histB = imin(384, half1 / 2);
            const int scb   = imin(384, half2 / 2);

            if (histB >= 1 && scb >= 1) {
                k1_hist_fused<<<half1 + histB, K1_THREADS, 0, stream>>>(
                    x, W1, XW, N, half1, arow, cnt, E, histB);
                csr_scan<<<1, SCAN_T, 0, stream>>>(cnt, rowptr, cursor, N);
                k1_scatter_fused<<<half2 + scb, K1_THREADS, 0, stream>>>(
                    x, W1, XW, N, half1, half2, arow, acol, aval, cursor, ecv, E, scb);
            } else {
                csr_hist<<<eb, 256, 0, stream>>>(arow, cnt, E);
                csr_scan<<<1, SCAN_T, 0, stream>>>(cnt, rowptr, cursor, N);
                csr_scatter<<<eb, 256, 0, stream>>>(arow, acol, aval, cursor, ecv, E);
                gcn_k1_xw<<<k1b, K1_THREADS, 0, stream>>>(x, W1, XW, N);
            }

            spmm16_h2<<<(N + 3) / 4, 256, 0, stream>>>(rowptr, ecv, XW, b1, W2, h2, N);
            spmm7_lsm<<<(N + 3) / 4, 256, 0, stream>>>(rowptr, ecv, h2, b2, out, N);
            return;
        }
    }

    // ---- tier-3: atomic fallback ----
    {
        float* XWf = (float*)d_ws;
        float* Hf  = XWf + (size_t)N * HID;
        float* h2f = XWf;
        const int hz4 = (int)(((size_t)N * HID) / 4);
        zero_i32<<<(hz4 + 255) / 256, 256, 0, stream>>>((int4*)Hf, hz4);
        (void)hipMemsetAsync(out, 0, (size_t)N * OUTC * sizeof(float), stream);
        gcn_k1_xw<<<k1b, K1_THREADS, 0, stream>>>(x, W1, XWf, N);
        gcn_k2_spmm16_atomic<<<eb, 256, 0, stream>>>(arow, acol, aval, XWf, Hf, E);
        gcn_k3_h2<<<nb, 256, 0, stream>>>(Hf, b1, W2, h2f, N);
        gcn_k4_spmm7_atomic<<<eb, 256, 0, stream>>>(arow, acol, aval, h2f, out, E);
        gcn_k5_lsm<<<nb, 256, 0, stream>>>(out, b2, N);
    }
}